// Round 5
// baseline (1947.189 us; speedup 1.0000x reference)
//
#include <hip/hip_runtime.h>

// OnlineLSTM: B=8192, T=2048, I=1, H=50.
// R10: ZIG-ZAG PIPELINE. R3/R4 established the ~700-820 cyc/step exposed
// stall is the per-step dependency chain (ds_read -> MFMA -> gate chain ->
// store -> barrier) executed IN-PHASE by all concurrent units (R3: two
// barrier domains lockstep; R4: compiler schedules both ILP groups through
// identical phases). This version anti-phases two 16-row groups BY
// CONSTRUCTION: z (MFMA output) stays in registers across the barrier, and
// each inter-barrier interval pairs one group's gate+store with the OTHER
// group's read+MFMA:
//   P: gates(zB)->store hB ; read hA -> MFMA -> zA ; barrier
//   Q: gates(zA)->store hA ; read hB -> MFMA -> zB ; barrier
// Gate VALU work overlaps the other group's LDS latency + matrix-pipe work;
// MFMA/ds_read latency leave the critical chain (consumed after barrier).
// Single-buffered LDS per group (store->read always barrier-separated).
// Block = 32 rows (2 groups x 16), 4 waves, grid 256 = 1 block/CU.
// Per-row MFMA/gate/LDS arithmetic identical to the 1338-us kernel.

#define HID   50
#define NSTEP 2048
#define BPB   32     // 2 groups of 16 rows
#define HSTR  72     // fp16 elems per hbuf row

typedef _Float16 half8   __attribute__((ext_vector_type(8)));
typedef float    float4v __attribute__((ext_vector_type(4)));
typedef float    float2v __attribute__((ext_vector_type(2)));

__device__ __forceinline__ float2v lo2(float4v v) { float2v r; r[0] = v[0]; r[1] = v[1]; return r; }
__device__ __forceinline__ float2v hi2(float4v v) { float2v r; r[0] = v[2]; r[1] = v[3]; return r; }

__device__ __forceinline__ float2v exp2v(float2v x) {
    float2v r;
    r[0] = __builtin_amdgcn_exp2f(x[0]);
    r[1] = __builtin_amdgcn_exp2f(x[1]);
    return r;
}

// Two rows at once. zi,zf,zo = -log2e * raw; zg = 2log2e * raw (prescaled in
// weights). Returns h pair, updates c pair. Packed fp32 algebra; one rcp per
// division pair via rcp(D0*D1) * swapped-D trick.
__device__ __forceinline__ float2v gate_pairs2(float2v zi, float2v zf, float2v zg,
                                               float2v zo, float2v& c) {
    float2v ei = exp2v(zi);      // e^{-i_raw}
    float2v ef = exp2v(zf);
    float2v Eg = exp2v(zg);      // e^{2 g_raw}
    float2v eo = exp2v(zo);
    float2v t1  = (1.0f + ei) * (1.0f + Eg);
    float2v pf  = 1.0f + ef;
    float2v num = c * t1 + pf * (Eg - 1.0f);
    float2v D   = t1 * pf;
    float   rP  = __builtin_amdgcn_rcpf(D[0] * D[1]);
    float2v Dsw; Dsw[0] = D[1]; Dsw[1] = D[0];
    c = num * Dsw * rP;
    float2v a = 2.8853900817779268f * c;     // 2*log2e * c
    a[0] = fminf(fmaxf(a[0], -24.0f), 24.0f);
    a[1] = fminf(fmaxf(a[1], -24.0f), 24.0f);
    float2v Ec  = exp2v(a);                  // e^{2c}
    float2v den = (1.0f + eo) * (1.0f + Ec);
    float   rQ  = __builtin_amdgcn_rcpf(den[0] * den[1]);
    float2v dsw; dsw[0] = den[1]; dsw[1] = den[0];
    return (Ec - 1.0f) * dsw * rQ;           // sigma(o) * tanh(c)
}

__global__ __launch_bounds__(256, 1) void lstm_fused(
    const float* __restrict__ x,
    const float* __restrict__ W_ih,
    const float* __restrict__ W_hh,
    const float* __restrict__ b_ih,
    const float* __restrict__ b_hh,
    const float* __restrict__ W_lin,
    const float* __restrict__ b_lin,
    float* __restrict__ out)
{
    // [group][row][k] — single-buffered per group (store->read barrier-separated)
    __shared__ __align__(16) _Float16 hbuf[2][16][HSTR];

    const int tid  = threadIdx.x;
    const int wave = tid >> 6;
    const int lane = tid & 63;
    const int col  = lane & 15;
    const int quad = lane >> 4;
    const int b0   = blockIdx.x * BPB;
    const int j    = wave * 16 + col;

    // ---- init h buffers: zeros, x_0 at col 50, 1.0 at col 51 ----
    for (int i = tid; i < 2 * 16 * HSTR; i += 256)
        (&hbuf[0][0][0])[i] = (_Float16)0.0f;
    __syncthreads();
    if (tid < BPB) {
        int g = tid >> 4, r = tid & 15;
        hbuf[g][r][HID]     = (_Float16)x[(size_t)(b0 + tid) * NSTEP];
        hbuf[g][r][HID + 1] = (_Float16)1.0f;
    }

    // ---- persistent B fragments, prescaled per gate (shared by both groups) ----
    const float LOG2E = 1.4426950408889634f;
    half8 bfrag[4][2];
    for (int g = 0; g < 4; ++g) {
        const float sc = (g == 2) ? (2.0f * LOG2E) : (-LOG2E);
        for (int kt = 0; kt < 2; ++kt) {
            half8 f;
            #pragma unroll
            for (int jj = 0; jj < 8; ++jj) {
                int k = kt * 32 + quad * 8 + jj;
                float v = 0.0f;
                if (j < HID) {
                    int row = g * HID + j;
                    if (k < HID)           v = W_hh[row * HID + k];
                    else if (k == HID)     v = W_ih[row];
                    else if (k == HID + 1) v = b_ih[row] + b_hh[row];
                }
                f[jj] = (_Float16)(v * sc);
            }
            bfrag[g][kt] = f;
        }
    }

    // per-group cell state
    float2v cA01 = {0.f, 0.f}, cA23 = {0.f, 0.f};
    float2v cB01 = {0.f, 0.f}, cB23 = {0.f, 0.f};

    const bool xloader = (wave == 3) && (quad == 0);
    const float* xrowA = x + (size_t)(b0 + col) * NSTEP;        // group A rows
    const float* xrowB = x + (size_t)(b0 + 16 + col) * NSTEP;   // group B rows
    const float4v Z4 = {0.f, 0.f, 0.f, 0.f};

    __syncthreads();

    float4v zA0, zA1, zA2, zA3, zB0, zB1, zB2, zB3;

    // ---- prologue: zB = z_B(0) from hB(0) (zeros + x0) ----
    {
        const _Float16* ar = &hbuf[1][col][0];
        half8 a0 = *(const half8*)(ar + quad * 8);
        half8 a1 = *(const half8*)(ar + 32 + quad * 8);
        zB0 = __builtin_amdgcn_mfma_f32_16x16x32_f16(a0, bfrag[0][0], Z4, 0, 0, 0);
        zB1 = __builtin_amdgcn_mfma_f32_16x16x32_f16(a0, bfrag[1][0], Z4, 0, 0, 0);
        zB2 = __builtin_amdgcn_mfma_f32_16x16x32_f16(a0, bfrag[2][0], Z4, 0, 0, 0);
        zB3 = __builtin_amdgcn_mfma_f32_16x16x32_f16(a0, bfrag[3][0], Z4, 0, 0, 0);
        zB0 = __builtin_amdgcn_mfma_f32_16x16x32_f16(a1, bfrag[0][1], zB0, 0, 0, 0);
        zB1 = __builtin_amdgcn_mfma_f32_16x16x32_f16(a1, bfrag[1][1], zB1, 0, 0, 0);
        zB2 = __builtin_amdgcn_mfma_f32_16x16x32_f16(a1, bfrag[2][1], zB2, 0, 0, 0);
        zB3 = __builtin_amdgcn_mfma_f32_16x16x32_f16(a1, bfrag[3][1], zB3, 0, 0, 0);
    }
    __syncthreads();   // protect P's stores to hbuf[1] against prologue reads

    // Invariant entering iteration t: hbuf[0]=hA(t)+xA(t), hbuf[1]=hB(t)+xB(t),
    // zB = z_B(t).  P: gates zB -> hB(t+1), store; read hA(t) -> zA = z_A(t).
    //              Q: gates zA -> hA(t+1), store; read hB(t+1) -> zB = z_B(t+1).
    for (int t = 0; t < NSTEP; ++t) {
        // ---- interval P ----
        {
            float xn = 0.f;
            if (xloader) {
                int tt = (t + 1 < NSTEP) ? (t + 1) : (NSTEP - 1);
                xn = xrowB[tt];
            }
            const _Float16* ar = &hbuf[0][col][0];           // hA(t)
            half8 a0 = *(const half8*)(ar + quad * 8);
            half8 a1 = *(const half8*)(ar + 32 + quad * 8);
            float2v h01 = gate_pairs2(lo2(zB0), lo2(zB1), lo2(zB2), lo2(zB3), cB01);
            float2v h23 = gate_pairs2(hi2(zB0), hi2(zB1), hi2(zB2), hi2(zB3), cB23);
            zA0 = __builtin_amdgcn_mfma_f32_16x16x32_f16(a0, bfrag[0][0], Z4, 0, 0, 0);
            zA1 = __builtin_amdgcn_mfma_f32_16x16x32_f16(a0, bfrag[1][0], Z4, 0, 0, 0);
            zA2 = __builtin_amdgcn_mfma_f32_16x16x32_f16(a0, bfrag[2][0], Z4, 0, 0, 0);
            zA3 = __builtin_amdgcn_mfma_f32_16x16x32_f16(a0, bfrag[3][0], Z4, 0, 0, 0);
            zA0 = __builtin_amdgcn_mfma_f32_16x16x32_f16(a1, bfrag[0][1], zA0, 0, 0, 0);
            zA1 = __builtin_amdgcn_mfma_f32_16x16x32_f16(a1, bfrag[1][1], zA1, 0, 0, 0);
            zA2 = __builtin_amdgcn_mfma_f32_16x16x32_f16(a1, bfrag[2][1], zA2, 0, 0, 0);
            zA3 = __builtin_amdgcn_mfma_f32_16x16x32_f16(a1, bfrag[3][1], zA3, 0, 0, 0);
            if (j < HID) {
                hbuf[1][quad * 4 + 0][j] = (_Float16)h01[0];
                hbuf[1][quad * 4 + 1][j] = (_Float16)h01[1];
                hbuf[1][quad * 4 + 2][j] = (_Float16)h23[0];
                hbuf[1][quad * 4 + 3][j] = (_Float16)h23[1];
            }
            if (xloader)
                hbuf[1][col][HID] = (_Float16)xn;
            __syncthreads();
        }
        // ---- interval Q ----
        {
            float xn = 0.f;
            if (xloader) {
                int tt = (t + 1 < NSTEP) ? (t + 1) : (NSTEP - 1);
                xn = xrowA[tt];
            }
            const _Float16* ar = &hbuf[1][col][0];           // hB(t+1)
            half8 a0 = *(const half8*)(ar + quad * 8);
            half8 a1 = *(const half8*)(ar + 32 + quad * 8);
            float2v h01 = gate_pairs2(lo2(zA0), lo2(zA1), lo2(zA2), lo2(zA3), cA01);
            float2v h23 = gate_pairs2(hi2(zA0), hi2(zA1), hi2(zA2), hi2(zA3), cA23);
            zB0 = __builtin_amdgcn_mfma_f32_16x16x32_f16(a0, bfrag[0][0], Z4, 0, 0, 0);
            zB1 = __builtin_amdgcn_mfma_f32_16x16x32_f16(a0, bfrag[1][0], Z4, 0, 0, 0);
            zB2 = __builtin_amdgcn_mfma_f32_16x16x32_f16(a0, bfrag[2][0], Z4, 0, 0, 0);
            zB3 = __builtin_amdgcn_mfma_f32_16x16x32_f16(a0, bfrag[3][0], Z4, 0, 0, 0);
            zB0 = __builtin_amdgcn_mfma_f32_16x16x32_f16(a1, bfrag[0][1], zB0, 0, 0, 0);
            zB1 = __builtin_amdgcn_mfma_f32_16x16x32_f16(a1, bfrag[1][1], zB1, 0, 0, 0);
            zB2 = __builtin_amdgcn_mfma_f32_16x16x32_f16(a1, bfrag[2][1], zB2, 0, 0, 0);
            zB3 = __builtin_amdgcn_mfma_f32_16x16x32_f16(a1, bfrag[3][1], zB3, 0, 0, 0);
            if (j < HID) {
                hbuf[0][quad * 4 + 0][j] = (_Float16)h01[0];
                hbuf[0][quad * 4 + 1][j] = (_Float16)h01[1];
                hbuf[0][quad * 4 + 2][j] = (_Float16)h23[0];
                hbuf[0][quad * 4 + 3][j] = (_Float16)h23[1];
            }
            if (xloader)
                hbuf[0][col][HID] = (_Float16)xn;
            __syncthreads();
        }
    }

    // ---- epilogue: out[b] = h_last . W_lin + b_lin ----
    if (tid < BPB) {
        int g = tid >> 4, r = tid & 15;
        float s = b_lin[0];
        for (int k = 0; k < HID; ++k)
            s += (float)hbuf[g][r][k] * W_lin[k];
        out[b0 + tid] = s;
    }
}

extern "C" void kernel_launch(void* const* d_in, const int* in_sizes, int n_in,
                              void* d_out, int out_size, void* d_ws, size_t ws_size,
                              hipStream_t stream) {
    const float* x     = (const float*)d_in[0];
    const float* W_ih  = (const float*)d_in[1];
    const float* W_hh  = (const float*)d_in[2];
    const float* b_ih  = (const float*)d_in[3];
    const float* b_hh  = (const float*)d_in[4];
    const float* W_lin = (const float*)d_in[5];
    const float* b_lin = (const float*)d_in[6];
    float* outp = (float*)d_out;
    dim3 grid(8192 / BPB), block(256);
    hipLaunchKernelGGL(lstm_fused, grid, block, 0, stream,
                       x, W_ih, W_hh, b_ih, b_hh, W_lin, b_lin, outp);
}

// Round 6
// 1254.973 us; speedup vs baseline: 1.5516x; 1.5516x over previous
//
#include <hip/hip_runtime.h>

// OnlineLSTM: B=8192, T=2048, I=1, H=50.
// R11 = revert to R3 (best measured: 1337.6 us; 2 blocks/CU, 2 waves/SIMD —
// R4/R10 proved sacrificing the second hardware wave stream for software
// phasing always loses) + three additive tail-shorteners:
//  (1) x-prefetch depth 2: store the pre-loaded x[t+1] to LDS at step START,
//      then issue the load of x[t+2] -> ~1.5 steps of HBM-latency cover;
//      xloader wave can't be the barrier laggard.
//  (2) interleave stores with gates: write h01's rows before computing h23,
//      overlapping ds_write latency with the second gate chain.
//  (3) s_setprio(1) across the gate+store region: with 2 drifting barrier
//      domains per SIMD, prefer the wave in its chain-critical phase.
// Everything else bit-identical to R3: block = 16 rows, 4 waves, grid 512 =
// 2 blocks/CU, gate-major N=256 MFMA, K padded 50->64 (k=50 x_t, k=51 1.0),
// weights prescaled -log2e (i,f,o) / +2log2e (g), packed-fp32 gate algebra,
// one-shot anti-phase s_sleep stagger for odd blocks.

#define HID   50
#define NSTEP 2048
#define BPB   16
#define HSTR  72     // fp16 elems per hbuf row

typedef _Float16 half8   __attribute__((ext_vector_type(8)));
typedef float    float4v __attribute__((ext_vector_type(4)));
typedef float    float2v __attribute__((ext_vector_type(2)));

__device__ __forceinline__ float2v lo2(float4v v) { float2v r; r[0] = v[0]; r[1] = v[1]; return r; }
__device__ __forceinline__ float2v hi2(float4v v) { float2v r; r[0] = v[2]; r[1] = v[3]; return r; }

__device__ __forceinline__ float2v exp2v(float2v x) {
    float2v r;
    r[0] = __builtin_amdgcn_exp2f(x[0]);
    r[1] = __builtin_amdgcn_exp2f(x[1]);
    return r;
}

// Two rows at once. zi,zf,zo = -log2e * raw; zg = 2log2e * raw (prescaled in
// weights). Returns h pair, updates c pair. Packed fp32 algebra; one rcp per
// division pair via rcp(D0*D1) * swapped-D trick.
__device__ __forceinline__ float2v gate_pairs2(float2v zi, float2v zf, float2v zg,
                                               float2v zo, float2v& c) {
    float2v ei = exp2v(zi);      // e^{-i_raw}
    float2v ef = exp2v(zf);
    float2v Eg = exp2v(zg);      // e^{2 g_raw}
    float2v eo = exp2v(zo);
    float2v t1  = (1.0f + ei) * (1.0f + Eg);
    float2v pf  = 1.0f + ef;
    float2v num = c * t1 + pf * (Eg - 1.0f);
    float2v D   = t1 * pf;
    float   rP  = __builtin_amdgcn_rcpf(D[0] * D[1]);
    float2v Dsw; Dsw[0] = D[1]; Dsw[1] = D[0];
    c = num * Dsw * rP;
    float2v a = 2.8853900817779268f * c;     // 2*log2e * c
    a[0] = fminf(fmaxf(a[0], -24.0f), 24.0f);
    a[1] = fminf(fmaxf(a[1], -24.0f), 24.0f);
    float2v Ec  = exp2v(a);                  // e^{2c}
    float2v den = (1.0f + eo) * (1.0f + Ec);
    float   rQ  = __builtin_amdgcn_rcpf(den[0] * den[1]);
    float2v dsw; dsw[0] = den[1]; dsw[1] = den[0];
    return (Ec - 1.0f) * dsw * rQ;           // sigma(o) * tanh(c)
}

__global__ __launch_bounds__(256, 2) void lstm_fused(
    const float* __restrict__ x,
    const float* __restrict__ W_ih,
    const float* __restrict__ W_hh,
    const float* __restrict__ b_ih,
    const float* __restrict__ b_hh,
    const float* __restrict__ W_lin,
    const float* __restrict__ b_lin,
    float* __restrict__ out)
{
    __shared__ __align__(16) _Float16 hbuf[2][BPB][HSTR];

    const int tid  = threadIdx.x;
    const int wave = tid >> 6;
    const int lane = tid & 63;
    const int col  = lane & 15;
    const int quad = lane >> 4;
    const int b0   = blockIdx.x * BPB;
    const int j    = wave * 16 + col;

    // ---- init h buffers: zeros, x_0 at col 50, 1.0 at col 51 ----
    for (int i = tid; i < 2 * BPB * HSTR; i += 256)
        (&hbuf[0][0][0])[i] = (_Float16)0.0f;
    __syncthreads();
    if (tid < BPB) {
        hbuf[0][tid][HID]     = (_Float16)x[(size_t)(b0 + tid) * NSTEP];
        hbuf[0][tid][HID + 1] = (_Float16)1.0f;
        hbuf[1][tid][HID + 1] = (_Float16)1.0f;
    }

    // ---- persistent B fragments, prescaled per gate ----
    const float LOG2E = 1.4426950408889634f;
    half8 bfrag[4][2];
    for (int g = 0; g < 4; ++g) {
        const float sc = (g == 2) ? (2.0f * LOG2E) : (-LOG2E);
        for (int kt = 0; kt < 2; ++kt) {
            half8 f;
            #pragma unroll
            for (int jj = 0; jj < 8; ++jj) {
                int k = kt * 32 + quad * 8 + jj;
                float v = 0.0f;
                if (j < HID) {
                    int row = g * HID + j;
                    if (k < HID)           v = W_hh[row * HID + k];
                    else if (k == HID)     v = W_ih[row];
                    else if (k == HID + 1) v = b_ih[row] + b_hh[row];
                }
                f[jj] = (_Float16)(v * sc);
            }
            bfrag[g][kt] = f;
        }
    }

    float2v c01 = {0.f, 0.f};
    float2v c23 = {0.f, 0.f};
    const bool xloader = (wave == 3) && (quad == 0);
    const float* xrow = x + (size_t)(b0 + col) * NSTEP;
    const float4v Z4 = {0.f, 0.f, 0.f, 0.f};

    // prefetch x[1] for step 0's store (depth-2 pipeline)
    float xn_reg = 0.f;
    if (xloader)
        xn_reg = xrow[1 < NSTEP ? 1 : NSTEP - 1];

    __syncthreads();

    // ---- anti-phase stagger: odd blocks start ~960 cyc (half a step) late,
    // so the two barrier domains on each CU alternate issue/stall ----
    if (blockIdx.x & 1) {
        __builtin_amdgcn_s_sleep(15);
    }

#define STEP(CUR, NXT, T)                                                        \
    {                                                                            \
        /* (1) store pre-loaded x[T+1] early; issue load of x[T+2] */            \
        if (xloader)                                                             \
            hbuf[NXT][col][HID] = (_Float16)xn_reg;                              \
        float xn_new = 0.f;                                                      \
        if (xloader) {                                                           \
            int tt = (T) + 2;                                                    \
            if (tt > NSTEP - 1) tt = NSTEP - 1;                                  \
            xn_new = xrow[tt];                                                   \
        }                                                                        \
        const _Float16* arow = &hbuf[CUR][col][0];                               \
        half8 a0 = *(const half8*)(arow + quad * 8);                             \
        half8 a1 = *(const half8*)(arow + 32 + quad * 8);                        \
        float4v d0, d1, d2, d3;                                                  \
        d0 = __builtin_amdgcn_mfma_f32_16x16x32_f16(a0, bfrag[0][0], Z4, 0, 0, 0); \
        d1 = __builtin_amdgcn_mfma_f32_16x16x32_f16(a0, bfrag[1][0], Z4, 0, 0, 0); \
        d2 = __builtin_amdgcn_mfma_f32_16x16x32_f16(a0, bfrag[2][0], Z4, 0, 0, 0); \
        d3 = __builtin_amdgcn_mfma_f32_16x16x32_f16(a0, bfrag[3][0], Z4, 0, 0, 0); \
        d0 = __builtin_amdgcn_mfma_f32_16x16x32_f16(a1, bfrag[0][1], d0, 0, 0, 0); \
        d1 = __builtin_amdgcn_mfma_f32_16x16x32_f16(a1, bfrag[1][1], d1, 0, 0, 0); \
        d2 = __builtin_amdgcn_mfma_f32_16x16x32_f16(a1, bfrag[2][1], d2, 0, 0, 0); \
        d3 = __builtin_amdgcn_mfma_f32_16x16x32_f16(a1, bfrag[3][1], d3, 0, 0, 0); \
        /* (3) prioritize the chain-critical gate+store region */                \
        __builtin_amdgcn_s_setprio(1);                                           \
        /* (2) interleave: gates(lo) -> store -> gates(hi) -> store */           \
        float2v h01 = gate_pairs2(lo2(d0), lo2(d1), lo2(d2), lo2(d3), c01);      \
        if (j < HID) {                                                           \
            hbuf[NXT][quad * 4 + 0][j] = (_Float16)h01[0];                       \
            hbuf[NXT][quad * 4 + 1][j] = (_Float16)h01[1];                       \
        }                                                                        \
        float2v h23 = gate_pairs2(hi2(d0), hi2(d1), hi2(d2), hi2(d3), c23);      \
        if (j < HID) {                                                           \
            hbuf[NXT][quad * 4 + 2][j] = (_Float16)h23[0];                       \
            hbuf[NXT][quad * 4 + 3][j] = (_Float16)h23[1];                       \
        }                                                                        \
        __builtin_amdgcn_s_setprio(0);                                           \
        xn_reg = xn_new;                                                         \
        __syncthreads();                                                         \
    }

    for (int t = 0; t < NSTEP; t += 2) {
        STEP(0, 1, t)
        STEP(1, 0, t + 1)
    }
#undef STEP

    // ---- epilogue: out[b] = h_last . W_lin + b_lin ; final h is in hbuf[0] ----
    if (tid < BPB) {
        float s = b_lin[0];
        for (int k = 0; k < HID; ++k)
            s += (float)hbuf[0][tid][k] * W_lin[k];
        out[b0 + tid] = s;
    }
}

extern "C" void kernel_launch(void* const* d_in, const int* in_sizes, int n_in,
                              void* d_out, int out_size, void* d_ws, size_t ws_size,
                              hipStream_t stream) {
    const float* x     = (const float*)d_in[0];
    const float* W_ih  = (const float*)d_in[1];
    const float* W_hh  = (const float*)d_in[2];
    const float* b_ih  = (const float*)d_in[3];
    const float* b_hh  = (const float*)d_in[4];
    const float* W_lin = (const float*)d_in[5];
    const float* b_lin = (const float*)d_in[6];
    float* outp = (float*)d_out;
    dim3 grid(8192 / BPB), block(256);
    hipLaunchKernelGGL(lstm_fused, grid, block, 0, stream,
                       x, W_ih, W_hh, b_ih, b_hh, W_lin, b_lin, outp);
}